// Round 15
// baseline (825.289 us; speedup 1.0000x reference)
//
#include <hip/hip_runtime.h>

// SOHMM forward, MI355X gfx950 — round 15: R12 protocol + in-wave row-max + ping-pong ET.
// 256 blocks (j x ih) x 1024 threads, ONE barrier per step.
//  - y words in d_out carry tag 2s+1 in the f32 low byte (deterministic rounding);
//    consumers poll y directly (the per-step all-to-all transpose).
//  - Stabilizer: per-(j,b) row max of the polled row (R12-proven), computed IN-WAVE:
//    wave w owns b in {4w..4w+3}, lane = kg*4 + (b&3) -> shfl_xor masks 4/8/16/32
//    (R14-proven mapping). No LDS reduce, no extra barrier.
//  - Ping-pong ET/MbL buffers -> single __syncthreads per step (hazard: s+2 writes of
//    ET[p] are separated from s reads of ET[p] by s+1's barrier).
//  - Final y_final rendezvous via tagged mslot/fpart sweeps (R12 verbatim),
//    memset-rearmed every launch/replay.

#define Hd 128
#define Bd 64
#define Sd 128
#define Vd 32000
#define HBc (Hd * Bd)          // 8192
#define HHBc (Hd * Hd * Bd)    // 1048576
#define NBLK 256
#define NTHR 1024
#define EPSF 1e-12f
#define FTAG 200u
#define SLOTW ((size_t)NBLK * Bd)   // 16384 words

typedef __attribute__((ext_vector_type(4))) float f32x4;
typedef __attribute__((ext_vector_type(8))) short s16x8;
typedef __attribute__((ext_vector_type(4))) short s16x4;

__device__ __forceinline__ short f2bf(float f) {
  unsigned u = __builtin_bit_cast(unsigned, f);
  unsigned r = (u + 0x7fffu + ((u >> 16) & 1u)) >> 16;
  return (short)(r & 0xffffu);
}
__device__ __forceinline__ unsigned mono_enc(float f) {
  unsigned u = __builtin_bit_cast(unsigned, f);
  return u ^ ((u & 0x80000000u) ? 0xFFFFFFFFu : 0x80000000u);
}
__device__ __forceinline__ float mono_dec(unsigned m) {
  unsigned u = (m & 0x80000000u) ? (m ^ 0x80000000u) : ~m;
  return __builtin_bit_cast(float, u);
}
__device__ __forceinline__ unsigned packM(float f, unsigned tag) {
  return (tag << 24) | (mono_enc(f) >> 8);
}
__device__ __forceinline__ float decM(unsigned w) {
  return mono_dec((w & 0x00FFFFFFu) << 8);
}
__device__ __forceinline__ unsigned pack_y(float v, unsigned tag) {
  unsigned u = __builtin_bit_cast(unsigned, v);
  return ((u + 0x80u) & 0xFFFFFF00u) | tag;
}
__device__ __forceinline__ float as_f(unsigned u) { return __builtin_bit_cast(float, u); }
__device__ __forceinline__ unsigned pack24(float f, unsigned tag) {
  unsigned u = __builtin_bit_cast(unsigned, f);
  return ((u + 0x80u) & 0xFFFFFF00u) | tag;
}
__device__ __forceinline__ float dec24(unsigned v) {
  return __builtin_bit_cast(float, v & 0xFFFFFF00u);
}

// LLC-coherent accessors (agent scope -> sc1 both directions).
__device__ __forceinline__ unsigned ld_u32(const unsigned* p) {
  return __hip_atomic_load(p, __ATOMIC_RELAXED, __HIP_MEMORY_SCOPE_AGENT);
}
__device__ __forceinline__ void st_u32(unsigned* p, unsigned v) {
  __hip_atomic_store(p, v, __ATOMIC_RELAXED, __HIP_MEMORY_SCOPE_AGENT);
}

__global__ __launch_bounds__(NTHR) void sohmm_persistent(
    const int* __restrict__ ids, const float* __restrict__ alpha,
    const float* __restrict__ beta, const float* __restrict__ gamma,
    float* __restrict__ out, unsigned* __restrict__ mslot,
    unsigned* __restrict__ fpart) {
  const int tid = threadIdx.x;
  const int bid = blockIdx.x;
  const int j = bid >> 1;
  const int ih = bid & 1;
  const int lane = tid & 63;
  const int w = tid >> 6;        // wave 0..15
  const int l15 = lane & 15;
  const int g4 = lane >> 4;
  const int wi = w >> 2;         // i-tile 0..3 (MFMA mapping, R12)
  const int wb = w & 3;          // b-tile 0..3
  const int ti0 = ih * 64 + wi * 16;
  const int tb0 = wb * 16;
  const int bepi = tb0 + l15;    // epilogue b
  // poll mapping (R14-proven): wave w owns b in {4w..4w+3}
  const int pb = w * 4 + (lane & 3);   // b this lane polls/stages
  const int kg = lane >> 2;            // k-group 0..15
  const int k0 = kg * 8;
  const int sb = tid & 63;       // final-phase b
  const int sq = tid >> 6;       // final-phase group

  __shared__ __align__(16) short ET[2][64][132];  // ping-pong E^T[b][k] bf16
  __shared__ float MbL[2][64];                    // ping-pong row max per b
  __shared__ __align__(16) float ip_all[Sd][Bd];  // beta[j, ids[b, S-1-t]]
  __shared__ unsigned redSu[16][64];
  __shared__ float redF[16][64];
  __shared__ float wred[4][64];
  __shared__ float gex[128];

  // ---- A fragments (held in VGPRs for the whole kernel) ----
  s16x8 afrag[4];
  {
    const int i = ti0 + l15;
    const float* ap = alpha + ((size_t)i * Hd + j) * Hd;
#pragma unroll
    for (int kc = 0; kc < 4; ++kc) {
      const int k = kc * 32 + g4 * 8;
      f32x4 a0 = *(const f32x4*)(ap + k);
      f32x4 a1 = *(const f32x4*)(ap + k + 4);
      s16x8 f;
      f[0] = f2bf(a0[0]); f[1] = f2bf(a0[1]); f[2] = f2bf(a0[2]); f[3] = f2bf(a0[3]);
      f[4] = f2bf(a1[0]); f[5] = f2bf(a1[1]); f[6] = f2bf(a1[2]); f[7] = f2bf(a1[3]);
      afrag[kc] = f;
    }
  }

  // ---- phase 0: ip table, gamma stats, tagged y0 (R12 verbatim) ----
  for (int idx = tid; idx < Sd * Bd; idx += NTHR) {
    const int t = idx >> 6, b = idx & 63;
    ip_all[t][b] = beta[(size_t)j * Vd + ids[b * Sd + (Sd - 1 - t)]];
  }
  {
    float m = -3.4e38f;
#pragma unroll
    for (int c = 0; c < 4; ++c) {
      f32x4 g = *(const f32x4*)(gamma + (size_t)(c * NTHR + tid) * 4);
      m = fmaxf(fmaxf(fmaxf(m, g[0]), g[1]), fmaxf(g[2], g[3]));
    }
#pragma unroll
    for (int o = 32; o >= 1; o >>= 1) m = fmaxf(m, __shfl_xor(m, o, 64));
    if (lane == 0) redF[0][w] = m;
  }
  __syncthreads();  // ip_all + gamma partials visible
  {
    // tagged y0 stores (tag 1): this block's 64 i-rows
    const int r = tid >> 4;
    const int b4 = (tid & 15) * 4;
    unsigned* yw = (unsigned*)out + (size_t)((ih * 64 + r) * Hd + j) * Bd + b4;
#pragma unroll
    for (int e = 0; e < 4; ++e) st_u32(yw + e, pack_y(ip_all[0][b4 + e], 1u));
  }
  {
    float gm = redF[0][0];
#pragma unroll
    for (int q = 1; q < 16; ++q) gm = fmaxf(gm, redF[0][q]);
    float ss = 0.f;
#pragma unroll
    for (int c = 0; c < 4; ++c) {
      f32x4 g = *(const f32x4*)(gamma + (size_t)(c * NTHR + tid) * 4);
      ss += __expf(g[0] - gm) + __expf(g[1] - gm) + __expf(g[2] - gm) + __expf(g[3] - gm);
    }
#pragma unroll
    for (int o = 32; o >= 1; o >>= 1) ss += __shfl_xor(ss, o, 64);
    if (lane == 0) redF[1][w] = ss;
    __syncthreads();
    float gs = 0.f;
#pragma unroll
    for (int q = 0; q < 16; ++q) gs += redF[1][q];
    if (tid < 128) gex[tid] = __expf(gamma[(size_t)tid * Hd + j] - gm) * (1.f / gs);
  }
  __syncthreads();

  // ---- main scan: s = 1 .. 127 — ONE barrier per step ----
  float val[4];
  int p = 0;
#pragma unroll 1
  for (int s = 1; s < Sd; ++s) {
    const unsigned ytag = (unsigned)(2 * s - 1);   // tag of y_{s-1}
    const unsigned wtag = (unsigned)(2 * s + 1);   // tag on y_s

    // 1) poll this thread's 8 y_{s-1} words (k = k0.., b = pb)
    const unsigned* ypw = (const unsigned*)out + (size_t)(s - 1) * HHBc + (size_t)j * HBc + pb;
    unsigned g[8];
#pragma unroll
    for (int e = 0; e < 8; ++e) g[e] = ld_u32(ypw + (size_t)(k0 + e) * Bd);
    {
      unsigned spins = 0;
      for (;;) {
        unsigned bad = 0;
#pragma unroll
        for (int e = 0; e < 8; ++e) bad |= (g[e] & 0xFFu) ^ ytag;
        if (!bad) break;
        if (++spins > (1u << 18)) break;
        __builtin_amdgcn_s_sleep(1);
#pragma unroll
        for (int e = 0; e < 8; ++e)
          if ((g[e] & 0xFFu) != ytag) g[e] = ld_u32(ypw + (size_t)(k0 + e) * Bd);
      }
    }

    // 2) in-wave row max for b = pb (16 lanes stride 4: masks 4,8,16,32)
    float pm = as_f(g[0]);
#pragma unroll
    for (int e = 1; e < 8; ++e) pm = fmaxf(pm, as_f(g[e]));
    pm = fmaxf(pm, __shfl_xor(pm, 4, 64));
    pm = fmaxf(pm, __shfl_xor(pm, 8, 64));
    pm = fmaxf(pm, __shfl_xor(pm, 16, 64));
    pm = fmaxf(pm, __shfl_xor(pm, 32, 64));

    // 3) stage E^T = bf16(exp(y - rowmax)), args <= 0; publish MbL
    {
      s16x8 uv;
#pragma unroll
      for (int e = 0; e < 8; ++e) ((short*)&uv)[e] = f2bf(__expf(as_f(g[e]) - pm));
      *(s16x8*)&ET[p][pb][k0] = uv;
      if (kg == 0) MbL[p][pb] = pm;
    }
    __syncthreads();  // THE barrier: ET[p] + MbL[p] ready

    // 4) MFMA: one 16x16 tile per wave (R12 mapping)
    f32x4 acc = (f32x4){0.f, 0.f, 0.f, 0.f};
#pragma unroll
    for (int kc = 0; kc < 4; ++kc) {
      const int kk = kc * 32 + g4 * 8;
      union { s16x4 h[2]; s16x8 v; } u;
      u.h[0] = *(const s16x4*)&ET[p][bepi][kk];
      u.h[1] = *(const s16x4*)&ET[p][bepi][kk + 4];
      acc = __builtin_amdgcn_mfma_f32_16x16x32_bf16(afrag[kc], u.v, acc, 0, 0, 0);
    }

    // 5) epilogue: val = log(acc+eps) + M + ip ; tagged y stores
    {
      const float add = MbL[p][bepi] + ip_all[s][bepi];
      unsigned* ycw = (unsigned*)out + (size_t)s * HHBc;
#pragma unroll
      for (int r = 0; r < 4; ++r) {
        float vv = __logf(acc[r] + EPSF) + add;
        val[r] = vv;
        st_u32(ycw + (size_t)(ti0 + g4 * 4 + r) * HBc + j * Bd + bepi, pack_y(vv, wtag));
      }
    }
    p ^= 1;  // ping-pong; next step's writes hit the other buffer
  }

  // ---- final: ONE global M rendezvous, then y_final (R12 verbatim) ----
  {
    float mx = fmaxf(fmaxf(val[0], val[1]), fmaxf(val[2], val[3]));
    mx = fmaxf(mx, __shfl_xor(mx, 16, 64));
    mx = fmaxf(mx, __shfl_xor(mx, 32, 64));
    if (lane < 16) wred[wi][tb0 + lane] = mx;
  }
  __syncthreads();
  if (tid < 64) {
    float m = fmaxf(fmaxf(wred[0][tid], wred[1][tid]), fmaxf(wred[2][tid], wred[3][tid]));
    st_u32(mslot + (size_t)bid * Bd + tid, packM(m, 1u));
  }
  // sweep all 256 producers (tag 1)
  {
    const unsigned* pm = mslot + (size_t)(sq * 16) * Bd + sb;
    unsigned g2[16];
#pragma unroll
    for (int q = 0; q < 16; ++q) g2[q] = ld_u32(pm + (size_t)q * Bd);
    unsigned spins = 0;
    for (;;) {
      unsigned bad = 0;
#pragma unroll
      for (int q = 0; q < 16; ++q) bad |= (g2[q] >> 24) ^ 1u;
      if (!bad) break;
      if (++spins > (1u << 18)) break;
      __builtin_amdgcn_s_sleep(1);
#pragma unroll
      for (int q = 0; q < 16; ++q)
        if ((g2[q] >> 24) != 1u) g2[q] = ld_u32(pm + (size_t)q * Bd);
    }
    unsigned mx = 0u;
#pragma unroll
    for (int q = 0; q < 16; ++q) mx = g2[q] > mx ? g2[q] : mx;
    redSu[sq][sb] = mx;
  }
  __syncthreads();
  {
    unsigned mxe = 0u;
#pragma unroll
    for (int q = 0; q < 16; ++q) mxe = redSu[q][bepi] > mxe ? redSu[q][bepi] : mxe;
    const float M = decM(mxe);
    float sum = 0.f;
#pragma unroll
    for (int r = 0; r < 4; ++r)
      sum += gex[ti0 + g4 * 4 + r] * __expf(fminf(val[r] - M, 1.0f));
    sum += __shfl_xor(sum, 16, 64);
    sum += __shfl_xor(sum, 32, 64);
    if (lane < 16) wred[wi][tb0 + lane] = sum;
  }
  __syncthreads();
  if (tid < 64) {
    float sm = wred[0][tid] + wred[1][tid] + wred[2][tid] + wred[3][tid];
    st_u32(fpart + (size_t)bid * Bd + tid, pack24(sm, FTAG));
  }

  if (bid == 0) {
    const unsigned* pm = fpart + (size_t)(sq * 16) * Bd + sb;
    unsigned g[16];
#pragma unroll
    for (int q = 0; q < 16; ++q) g[q] = ld_u32(pm + (size_t)q * Bd);
    {
      unsigned spins = 0;
      for (;;) {
        unsigned bad = 0;
#pragma unroll
        for (int q = 0; q < 16; ++q) bad |= (g[q] & 0xFFu) ^ FTAG;
        if (!bad) break;
        if (++spins > (1u << 18)) break;
        __builtin_amdgcn_s_sleep(1);
#pragma unroll
        for (int q = 0; q < 16; ++q)
          if ((g[q] & 0xFFu) != FTAG) g[q] = ld_u32(pm + (size_t)q * Bd);
      }
    }
    float s16v = 0.f;
#pragma unroll
    for (int q = 0; q < 16; ++q) s16v += dec24(g[q]);
    redF[sq][sb] = s16v;
    __syncthreads();
    if (tid < 64) {
      unsigned mxe = 0u;
#pragma unroll
      for (int q = 0; q < 16; ++q) mxe = redSu[q][tid] > mxe ? redSu[q][tid] : mxe;
      float tot = 0.f;
#pragma unroll
      for (int q = 0; q < 16; ++q) tot += redF[q][tid];
      out[(size_t)Sd * HHBc + tid] = __logf(tot + EPSF) + decM(mxe);
    }
  }
}

extern "C" void kernel_launch(void* const* d_in, const int* in_sizes, int n_in,
                              void* d_out, int out_size, void* d_ws, size_t ws_size,
                              hipStream_t stream) {
  const int* ids = (const int*)d_in[0];
  const float* alpha = (const float*)d_in[1];
  const float* beta = (const float*)d_in[2];
  const float* gamma = (const float*)d_in[3];
  float* out = (float*)d_out;
  unsigned* mslot = (unsigned*)d_ws;               // [256][64] u32 = 64 KB (final M)
  unsigned* fpart = mslot + SLOTW;                 // [256][64] u32 = 64 KB

  // Re-arm the final-phase gates every launch (graph node, re-runs each replay).
  hipMemsetAsync(mslot, 0, 2 * SLOTW * sizeof(unsigned), stream);
  hipLaunchKernelGGL(sohmm_persistent, dim3(NBLK), dim3(NTHR), 0, stream,
                     ids, alpha, beta, gamma, out, mslot, fpart);
}

// Round 16
// 446.398 us; speedup vs baseline: 1.8488x; 1.8488x over previous
//
#include <hip/hip_runtime.h>

// SOHMM forward, MI355X gfx950 — round 16: REVERT to round-12 kernel (best: 447us).
// 256 blocks (j x ih) x 1024 threads, 2 barriers/step.
//  - y words in d_out carry tag 2s+1 in the f32 low byte (deterministic rounding);
//    consumers poll y directly -> one LLC trip per step (the ONLY cross-block traffic
//    in the scan; it embodies the per-step 128x128 transpose).
//  - Stabilizer: block-local per-b max of the polled row (>= row max -> exp args <= 0).
//    Deterministic (computed from tagged y bits). Validated R12: absmax 8.0.
//  - ONE global M rendezvous before y_final (cross-block-consistent scale) via
//    tagged mslot sweep; fpart partial sums; both memset-rearmed per replay.

#define Hd 128
#define Bd 64
#define Sd 128
#define Vd 32000
#define HBc (Hd * Bd)          // 8192
#define HHBc (Hd * Hd * Bd)    // 1048576
#define NBLK 256
#define NTHR 1024
#define EPSF 1e-12f
#define FTAG 200u
#define SLOTW ((size_t)NBLK * Bd)   // 16384 words

typedef __attribute__((ext_vector_type(4))) float f32x4;
typedef __attribute__((ext_vector_type(8))) short s16x8;
typedef __attribute__((ext_vector_type(4))) short s16x4;

__device__ __forceinline__ short f2bf(float f) {
  unsigned u = __builtin_bit_cast(unsigned, f);
  unsigned r = (u + 0x7fffu + ((u >> 16) & 1u)) >> 16;
  return (short)(r & 0xffffu);
}
__device__ __forceinline__ unsigned mono_enc(float f) {
  unsigned u = __builtin_bit_cast(unsigned, f);
  return u ^ ((u & 0x80000000u) ? 0xFFFFFFFFu : 0x80000000u);
}
__device__ __forceinline__ float mono_dec(unsigned m) {
  unsigned u = (m & 0x80000000u) ? (m ^ 0x80000000u) : ~m;
  return __builtin_bit_cast(float, u);
}
__device__ __forceinline__ unsigned packM(float f, unsigned tag) {
  return (tag << 24) | (mono_enc(f) >> 8);
}
__device__ __forceinline__ float decM(unsigned w) {
  return mono_dec((w & 0x00FFFFFFu) << 8);
}
__device__ __forceinline__ unsigned pack_y(float v, unsigned tag) {
  unsigned u = __builtin_bit_cast(unsigned, v);
  return ((u + 0x80u) & 0xFFFFFF00u) | tag;
}
__device__ __forceinline__ float as_f(unsigned u) { return __builtin_bit_cast(float, u); }
__device__ __forceinline__ unsigned pack24(float f, unsigned tag) {
  unsigned u = __builtin_bit_cast(unsigned, f);
  return ((u + 0x80u) & 0xFFFFFF00u) | tag;
}
__device__ __forceinline__ float dec24(unsigned v) {
  return __builtin_bit_cast(float, v & 0xFFFFFF00u);
}

// LLC-coherent accessors (agent scope -> sc1 both directions).
__device__ __forceinline__ unsigned ld_u32(const unsigned* p) {
  return __hip_atomic_load(p, __ATOMIC_RELAXED, __HIP_MEMORY_SCOPE_AGENT);
}
__device__ __forceinline__ void st_u32(unsigned* p, unsigned v) {
  __hip_atomic_store(p, v, __ATOMIC_RELAXED, __HIP_MEMORY_SCOPE_AGENT);
}

__global__ __launch_bounds__(NTHR) void sohmm_persistent(
    const int* __restrict__ ids, const float* __restrict__ alpha,
    const float* __restrict__ beta, const float* __restrict__ gamma,
    float* __restrict__ out, unsigned* __restrict__ mslot,
    unsigned* __restrict__ fpart) {
  const int tid = threadIdx.x;
  const int bid = blockIdx.x;
  const int j = bid >> 1;
  const int ih = bid & 1;
  const int lane = tid & 63;
  const int w = tid >> 6;        // wave 0..15
  const int l15 = lane & 15;
  const int g4 = lane >> 4;
  const int wi = w >> 2;         // i-tile 0..3
  const int wb = w & 3;          // b-tile 0..3
  const int ti0 = ih * 64 + wi * 16;
  const int tb0 = wb * 16;
  const int bepi = tb0 + l15;    // epilogue b
  const int sb = tid & 63;       // staging b
  const int sq = tid >> 6;       // staging k-group

  __shared__ __align__(16) short ET[64][132];     // E^T[b][k] bf16 (stride 264 B)
  __shared__ __align__(16) float ip_all[Sd][Bd];  // beta[j, ids[b, S-1-t]]
  __shared__ float redM[16][64];                  // local-max partials
  __shared__ unsigned redSu[16][64];              // final sweep partials
  __shared__ float redF[16][64];
  __shared__ float wred[4][64];
  __shared__ float gex[128];

  // ---- A fragments (held in VGPRs for the whole kernel) ----
  s16x8 afrag[4];
  {
    const int i = ti0 + l15;
    const float* ap = alpha + ((size_t)i * Hd + j) * Hd;
#pragma unroll
    for (int kc = 0; kc < 4; ++kc) {
      const int k = kc * 32 + g4 * 8;
      f32x4 a0 = *(const f32x4*)(ap + k);
      f32x4 a1 = *(const f32x4*)(ap + k + 4);
      s16x8 f;
      f[0] = f2bf(a0[0]); f[1] = f2bf(a0[1]); f[2] = f2bf(a0[2]); f[3] = f2bf(a0[3]);
      f[4] = f2bf(a1[0]); f[5] = f2bf(a1[1]); f[6] = f2bf(a1[2]); f[7] = f2bf(a1[3]);
      afrag[kc] = f;
    }
  }

  // ---- phase 0: ip table, gamma stats, tagged y0 ----
  for (int idx = tid; idx < Sd * Bd; idx += NTHR) {
    const int t = idx >> 6, b = idx & 63;
    ip_all[t][b] = beta[(size_t)j * Vd + ids[b * Sd + (Sd - 1 - t)]];
  }
  {
    float m = -3.4e38f;
#pragma unroll
    for (int c = 0; c < 4; ++c) {
      f32x4 g = *(const f32x4*)(gamma + (size_t)(c * NTHR + tid) * 4);
      m = fmaxf(fmaxf(fmaxf(m, g[0]), g[1]), fmaxf(g[2], g[3]));
    }
#pragma unroll
    for (int o = 32; o >= 1; o >>= 1) m = fmaxf(m, __shfl_xor(m, o, 64));
    if (lane == 0) redF[0][w] = m;
  }
  __syncthreads();  // ip_all + gamma partials visible
  {
    // tagged y0 stores (tag 1): this block's 64 i-rows
    const int r = tid >> 4;
    const int b4 = (tid & 15) * 4;
    unsigned* yw = (unsigned*)out + (size_t)((ih * 64 + r) * Hd + j) * Bd + b4;
#pragma unroll
    for (int e = 0; e < 4; ++e) st_u32(yw + e, pack_y(ip_all[0][b4 + e], 1u));
  }
  {
    float gm = redF[0][0];
#pragma unroll
    for (int q = 1; q < 16; ++q) gm = fmaxf(gm, redF[0][q]);
    float ss = 0.f;
#pragma unroll
    for (int c = 0; c < 4; ++c) {
      f32x4 g = *(const f32x4*)(gamma + (size_t)(c * NTHR + tid) * 4);
      ss += __expf(g[0] - gm) + __expf(g[1] - gm) + __expf(g[2] - gm) + __expf(g[3] - gm);
    }
#pragma unroll
    for (int o = 32; o >= 1; o >>= 1) ss += __shfl_xor(ss, o, 64);
    if (lane == 0) redF[1][w] = ss;
    __syncthreads();
    float gs = 0.f;
#pragma unroll
    for (int q = 0; q < 16; ++q) gs += redF[1][q];
    if (tid < 128) gex[tid] = __expf(gamma[(size_t)tid * Hd + j] - gm) * (1.f / gs);
  }
  __syncthreads();

  // ---- main scan: s = 1 .. 127 (2 barriers/step, no global M) ----
  float val[4];
#pragma unroll 1
  for (int s = 1; s < Sd; ++s) {
    const unsigned ytag = (unsigned)(2 * s - 1);   // tag of y_{s-1}
    const unsigned wtag = (unsigned)(2 * s + 1);   // tag on y_s

    // 1) poll this thread's 8 y_{s-1} words (k = sq*8.., b = sb)
    const int k0 = sq * 8;
    const unsigned* ypw = (const unsigned*)out + (size_t)(s - 1) * HHBc + (size_t)j * HBc + sb;
    unsigned g[8];
#pragma unroll
    for (int e = 0; e < 8; ++e) g[e] = ld_u32(ypw + (size_t)(k0 + e) * Bd);
    {
      unsigned spins = 0;
      for (;;) {
        unsigned bad = 0;
#pragma unroll
        for (int e = 0; e < 8; ++e) bad |= (g[e] & 0xFFu) ^ ytag;
        if (!bad) break;
        if (++spins > (1u << 18)) break;
        __builtin_amdgcn_s_sleep(1);
#pragma unroll
        for (int e = 0; e < 8; ++e)
          if ((g[e] & 0xFFu) != ytag) g[e] = ld_u32(ypw + (size_t)(k0 + e) * Bd);
      }
    }

    // 2) local-max partial over this thread's 8 k's
    {
      float pm = as_f(g[0]);
#pragma unroll
      for (int e = 1; e < 8; ++e) pm = fmaxf(pm, as_f(g[e]));
      redM[sq][sb] = pm;
    }
    __syncthreads();  // B1: redM partials ready

    // 3) column reduces: Mst (staging b=sb), Madd (epilogue b=bepi, broadcast)
    float Mst = redM[0][sb];
#pragma unroll
    for (int q = 1; q < 16; ++q) Mst = fmaxf(Mst, redM[q][sb]);
    float Me = redM[0][bepi];
#pragma unroll
    for (int q = 1; q < 16; ++q) Me = fmaxf(Me, redM[q][bepi]);
    const float add = Me + ip_all[s][bepi];

    // 4) stage E^T = bf16(exp(y - Mlocal)); args provably <= 0
    {
      union { s16x8 v; } u;
#pragma unroll
      for (int e = 0; e < 8; ++e)
        ((short*)&u.v)[e] = f2bf(__expf(as_f(g[e]) - Mst));
      *(s16x8*)&ET[sb][k0] = u.v;
    }
    __syncthreads();  // B2: ET ready (also fences redM reads vs next-iter writes)

    // 5) MFMA: one 16x16 tile per wave
    f32x4 acc = (f32x4){0.f, 0.f, 0.f, 0.f};
#pragma unroll
    for (int kc = 0; kc < 4; ++kc) {
      const int kk = kc * 32 + g4 * 8;
      union { s16x4 h[2]; s16x8 v; } u;
      u.h[0] = *(const s16x4*)&ET[bepi][kk];
      u.h[1] = *(const s16x4*)&ET[bepi][kk + 4];
      acc = __builtin_amdgcn_mfma_f32_16x16x32_bf16(afrag[kc], u.v, acc, 0, 0, 0);
    }

    // 6) epilogue: val = log(acc+eps) + Mlocal + ip, tagged y stores
    {
      unsigned* ycw = (unsigned*)out + (size_t)s * HHBc;
#pragma unroll
      for (int r = 0; r < 4; ++r) {
        float vv = __logf(acc[r] + EPSF) + add;
        val[r] = vv;
        st_u32(ycw + (size_t)(ti0 + g4 * 4 + r) * HBc + j * Bd + bepi, pack_y(vv, wtag));
      }
    }
    // no barrier needed here: next-iter redM writes are ordered by B1-next arrival,
    // and B2-this already separates them from this-iter redM/ET reads.
  }

  // ---- final: ONE global M rendezvous, then y_final ----
  // per-wave per-b max of val
  {
    float mx = fmaxf(fmaxf(val[0], val[1]), fmaxf(val[2], val[3]));
    mx = fmaxf(mx, __shfl_xor(mx, 16, 64));
    mx = fmaxf(mx, __shfl_xor(mx, 32, 64));
    if (lane < 16) wred[wi][tb0 + lane] = mx;
  }
  __syncthreads();
  if (tid < 64) {
    float m = fmaxf(fmaxf(wred[0][tid], wred[1][tid]), fmaxf(wred[2][tid], wred[3][tid]));
    st_u32(mslot + (size_t)bid * Bd + tid, packM(m, 1u));
  }
  // sweep all 256 producers (tag 1)
  {
    const unsigned* pm = mslot + (size_t)(sq * 16) * Bd + sb;
    unsigned g2[16];
#pragma unroll
    for (int q = 0; q < 16; ++q) g2[q] = ld_u32(pm + (size_t)q * Bd);
    unsigned spins = 0;
    for (;;) {
      unsigned bad = 0;
#pragma unroll
      for (int q = 0; q < 16; ++q) bad |= (g2[q] >> 24) ^ 1u;
      if (!bad) break;
      if (++spins > (1u << 18)) break;
      __builtin_amdgcn_s_sleep(1);
#pragma unroll
      for (int q = 0; q < 16; ++q)
        if ((g2[q] >> 24) != 1u) g2[q] = ld_u32(pm + (size_t)q * Bd);
    }
    unsigned mx = 0u;
#pragma unroll
    for (int q = 0; q < 16; ++q) mx = g2[q] > mx ? g2[q] : mx;
    redSu[sq][sb] = mx;
  }
  __syncthreads();
  // partial sums with the common M
  {
    unsigned mxe = 0u;
#pragma unroll
    for (int q = 0; q < 16; ++q) mxe = redSu[q][bepi] > mxe ? redSu[q][bepi] : mxe;
    const float M = decM(mxe);
    float sum = 0.f;
#pragma unroll
    for (int r = 0; r < 4; ++r)
      sum += gex[ti0 + g4 * 4 + r] * __expf(fminf(val[r] - M, 1.0f));
    sum += __shfl_xor(sum, 16, 64);
    sum += __shfl_xor(sum, 32, 64);
    if (lane < 16) wred[wi][tb0 + lane] = sum;
  }
  __syncthreads();
  if (tid < 64) {
    float sm = wred[0][tid] + wred[1][tid] + wred[2][tid] + wred[3][tid];
    st_u32(fpart + (size_t)bid * Bd + tid, pack24(sm, FTAG));
  }

  if (bid == 0) {
    const unsigned* pm = fpart + (size_t)(sq * 16) * Bd + sb;
    unsigned g[16];
#pragma unroll
    for (int q = 0; q < 16; ++q) g[q] = ld_u32(pm + (size_t)q * Bd);
    {
      unsigned spins = 0;
      for (;;) {
        unsigned bad = 0;
#pragma unroll
        for (int q = 0; q < 16; ++q) bad |= (g[q] & 0xFFu) ^ FTAG;
        if (!bad) break;
        if (++spins > (1u << 18)) break;
        __builtin_amdgcn_s_sleep(1);
#pragma unroll
        for (int q = 0; q < 16; ++q)
          if ((g[q] & 0xFFu) != FTAG) g[q] = ld_u32(pm + (size_t)q * Bd);
      }
    }
    float s16v = 0.f;
#pragma unroll
    for (int q = 0; q < 16; ++q) s16v += dec24(g[q]);
    redF[sq][sb] = s16v;
    __syncthreads();
    if (tid < 64) {
      unsigned mxe = 0u;
#pragma unroll
      for (int q = 0; q < 16; ++q) mxe = redSu[q][tid] > mxe ? redSu[q][tid] : mxe;
      float tot = 0.f;
#pragma unroll
      for (int q = 0; q < 16; ++q) tot += redF[q][tid];
      out[(size_t)Sd * HHBc + tid] = __logf(tot + EPSF) + decM(mxe);
    }
  }
}

extern "C" void kernel_launch(void* const* d_in, const int* in_sizes, int n_in,
                              void* d_out, int out_size, void* d_ws, size_t ws_size,
                              hipStream_t stream) {
  const int* ids = (const int*)d_in[0];
  const float* alpha = (const float*)d_in[1];
  const float* beta = (const float*)d_in[2];
  const float* gamma = (const float*)d_in[3];
  float* out = (float*)d_out;
  unsigned* mslot = (unsigned*)d_ws;               // [256][64] u32 = 64 KB (final M)
  unsigned* fpart = mslot + SLOTW;                 // [256][64] u32 = 64 KB

  // Re-arm the final-phase gates every launch (graph node, re-runs each replay).
  hipMemsetAsync(mslot, 0, 2 * SLOTW * sizeof(unsigned), stream);
  hipLaunchKernelGGL(sohmm_persistent, dim3(NBLK), dim3(NTHR), 0, stream,
                     ids, alpha, beta, gamma, out, mslot, fpart);
}